// Round 15
// baseline (768.011 us; speedup 1.0000x reference)
//
#include <hip/hip_runtime.h>
#include <math.h>

#define NB 8
#define NH 256
#define NW 256
#define NC 180
#define NE 6
#define HD 30
#define NL 256
#define NK 64
#define NWIN 2048

typedef __attribute__((ext_vector_type(8))) short bf16x8;
typedef __attribute__((ext_vector_type(4))) float f32x4;

union FU { bf16x8 f; unsigned u[4]; unsigned short s[8]; };

static __device__ __forceinline__ unsigned short f2bf(float x) {
    unsigned u = __float_as_uint(x);
    unsigned r = (u + 0x7FFFu + ((u >> 16) & 1u)) >> 16;
    return (unsigned short)r;
}
static __device__ __forceinline__ unsigned pk2(float a, float b) {
    return (unsigned)f2bf(a) | ((unsigned)f2bf(b) << 16);
}
// fragment load: elements {p[0..3], p[16..19]} — 8B-aligned rows
static __device__ __forceinline__ bf16x8 ld8(const unsigned short* p) {
    FU t;
    *(uint2*)&t.u[0] = *(const uint2*)p;
    *(uint2*)&t.u[2] = *(const uint2*)(p + 16);
    return t.f;
}
// same element order, 4B-aligned rows (stride-34 LDS)
static __device__ __forceinline__ bf16x8 ld8q(const unsigned short* p) {
    FU t;
    t.u[0] = *(const unsigned*)p;
    t.u[1] = *(const unsigned*)(p + 2);
    t.u[2] = *(const unsigned*)(p + 16);
    t.u[3] = *(const unsigned*)(p + 18);
    return t.f;
}

// ---------------------------------------------------------------------------
// k_xbf: x (fp32) -> xbf (bf16), EXACT same f2bf as the old inline path.
// 8 elems/thread; 94371840/8/256 = 46080 blocks exactly.
// ---------------------------------------------------------------------------
__global__ __launch_bounds__(256) void k_xbf(
    const float* __restrict__ x, unsigned short* __restrict__ xbf)
{
    long i = ((long)blockIdx.x * 256 + threadIdx.x) * 8;
    float4 a = *(const float4*)(x + i);
    float4 b = *(const float4*)(x + i + 4);
    uint4 o;
    o.x = pk2(a.x, a.y);
    o.y = pk2(a.z, a.w);
    o.z = pk2(b.x, b.y);
    o.w = pk2(b.z, b.w);
    *(uint4*)(xbf + i) = o;
}

// ---------------------------------------------------------------------------
// prep: Wqkv_t[h][n'<96][k<192] (n' = sec*32+r, n = sec*30+r; pads zero)
//       Wcomb_t[h][o<192][d<32] = (Wo[h] @ Wp^T)^T  (pads zero)
// ---------------------------------------------------------------------------
__global__ __launch_bounds__(256) void k_prep(
    const float* __restrict__ Wqkv, const float* __restrict__ Wo,
    const float* __restrict__ Wp,
    unsigned short* __restrict__ Wqkv_t, unsigned short* __restrict__ Wcomb_t)
{
    int i = blockIdx.x * 256 + threadIdx.x;
    if (i < NE * 96 * 192) {
        int h = i / (96 * 192), rm = i % (96 * 192), np = rm / 192, k = rm % 192;
        int sec = np >> 5, r = np & 31;
        float v = (r < 30 && k < NC) ? Wqkv[((long)h * NC + k) * 90 + sec * 30 + r] : 0.f;
        Wqkv_t[i] = f2bf(v);
    }
    if (i < NE * 192 * 32) {
        int h = i / (192 * 32), rm = i % (192 * 32), o = rm / 32, d = rm & 31;
        float acc = 0.f;
        if (o < NC && d < HD) {
            const float* wo = Wo + ((long)h * HD + d) * NC;
            const float* wp = Wp + (long)o * NC;
            for (int c = 0; c < NC; ++c) acc += wo[c] * wp[c];
        }
        Wcomb_t[i] = f2bf(acc);
    }
}

// ---------------------------------------------------------------------------
// Router: staging + logit + sigmoid phases VERBATIM from round 1 (those
// compiled float bits match the np reference's selection exactly — do not
// touch). Selection: exact bitonic sort on sigmoid bits (round-13-proven).
// ---------------------------------------------------------------------------
__global__ __launch_bounds__(256) void k_router_topk(
    const float* __restrict__ x, const float* __restrict__ Wr,
    int* __restrict__ idx_g, float* __restrict__ vals_g)
{
    __shared__ float wr_s[NE * NC];
    __shared__ __align__(16) float xs[32 * 181];   // overlaid by keys after logits
    __shared__ float lg[NE * NL];

    const int w   = blockIdx.x;
    const int tid = threadIdx.x;
    const int b = w >> 8, hb = (w >> 4) & 15, wb = w & 15;
    const long win_base = (((long)b * NH + hb * 16) * NW + wb * 16) * NC;

    for (int f = tid; f < NE * NC; f += 256) wr_s[f] = Wr[f];
    __syncthreads();

    for (int tile = 0; tile < 8; ++tile) {
        for (int f = tid; f < 32 * NC; f += 256) {
            int tl = f / NC, ch = f % NC;
            int tok = tile * 32 + tl;
            int r = tok >> 4, cl = tok & 15;
            xs[tl * 181 + ch] = x[win_base + ((long)r * NW + cl) * NC + ch];
        }
        __syncthreads();
        if (tid < 192) {
            int tl = tid & 31, e = tid >> 5;
            float acc = 0.f;
            for (int c = 0; c < NC; ++c) acc += xs[tl * 181 + c] * wr_s[e * NC + c];
            lg[e * NL + tile * 32 + tl] = 1.0f / (1.0f + expf(-acc));
        }
        __syncthreads();
    }

    // ---- exact top-63 via bitonic sort of composite keys (bits identical) --
    unsigned long long* keys = (unsigned long long*)xs;  // xs dead; barriers pin
    #pragma unroll
    for (int e = 0; e < NE; ++e) {
        unsigned kb = __float_as_uint(lg[e * NL + tid]);
        unsigned long long comp =
            ((unsigned long long)kb << 32) | (unsigned)(0xFFFFFFFFu - tid);
        if (tid == 0) comp = 0ull;   // token 0 excluded from ranked list
        keys[e * NL + tid] = comp;
    }
    __syncthreads();

    for (int k = 2; k <= 256; k <<= 1) {
        for (int j = k >> 1; j > 0; j >>= 1) {
            const int i = tid, ixj = i ^ j;
            if (ixj > i) {
                const bool up = ((i & k) == 0);
                #pragma unroll
                for (int e = 0; e < NE; ++e) {
                    unsigned long long a  = keys[e * NL + i];
                    unsigned long long bv = keys[e * NL + ixj];
                    bool sw = up ? (a < bv) : (a > bv);   // descending sort
                    if (sw) { keys[e * NL + i] = bv; keys[e * NL + ixj] = a; }
                }
            }
            __syncthreads();
        }
    }

    if (tid < NK - 1) {   // sorted position == rank; slots 1..63
        #pragma unroll
        for (int e = 0; e < NE; ++e) {
            unsigned long long kk = keys[e * NL + tid];
            int t = (int)(0xFFFFFFFFu - (unsigned)kk);
            idx_g[(w * NE + e) * NK + 1 + tid]  = t;
            vals_g[(w * NE + e) * NK + 1 + tid] = __uint_as_float((unsigned)(kk >> 32));
        }
    }
    if (tid == 0) {
        #pragma unroll
        for (int e = 0; e < NE; ++e) {
            idx_g[(w * NE + e) * NK]  = 0;
            vals_g[(w * NE + e) * NK] = lg[e * NL];
        }
    }
}

// ---------------------------------------------------------------------------
// k_attn: one WAVE per (window, head), w-major. Gathers from PRE-CONVERTED
// bf16 xbf (half the bytes, no inline f2bf). Algebra identical to round 12.
//   at_g[(h*2048 + w)*64 + slot][32] bf16  (cols 30,31 zero-pad)
// ---------------------------------------------------------------------------
__global__ __launch_bounds__(256, 3) void k_attn(
    const unsigned short* __restrict__ xbf,
    const unsigned short* __restrict__ Wqkv_t,
    const int* __restrict__ idx_g, const float* __restrict__ vals_g,
    unsigned short* __restrict__ at_g)
{
    __shared__ char sm[34816];
    const int tid = threadIdx.x;
    const int wv = tid >> 6;
    const int ln = tid & 63;
    const int lr = ln & 15;
    const int lg = ln >> 4;

    const int id = blockIdx.x * 4 + wv;      // w-major: id = w*6 + h
    const int w = id / 6;
    const int h = id % 6;
    const int b = w >> 8, hb = (w >> 4) & 15, wb = w & 15;
    const long win_base = (((long)b * NH + hb * 16) * NW + wb * 16) * NC;

    unsigned short* q_s = (unsigned short*)(sm + wv * 8704);
    unsigned short* k_s = q_s + 2176;

    int tokr[4];
    #pragma unroll
    for (int t = 0; t < 4; ++t)
        tokr[t] = idx_g[((long)w * NE + h) * NK + 16 * t + lr];

    // --- QKV = gather(xbf) @ Wqkv_t : M=64, N=96, K=192 ---
    f32x4 acc[6][4];
    #pragma unroll
    for (int nt = 0; nt < 6; ++nt)
        #pragma unroll
        for (int mt = 0; mt < 4; ++mt) acc[nt][mt] = (f32x4){0.f, 0.f, 0.f, 0.f};

    const unsigned short* bb = Wqkv_t + ((long)h * 96 + lr) * 192 + 4 * lg;
    #pragma unroll
    for (int kt = 0; kt < 6; ++kt) {
        bf16x8 Amt[4];
        #pragma unroll
        for (int mt = 0; mt < 4; ++mt) {
            const unsigned short* xr = xbf + win_base +
                ((long)(tokr[mt] >> 4) * NW + (tokr[mt] & 15)) * NC;
            if (kt < 5) {
                Amt[mt] = ld8(xr + 4 * lg + 32 * kt);
            } else {
                FU t;
                *(uint2*)&t.u[0] = *(const uint2*)(xr + 160 + 4 * lg);
                *(uint2*)&t.u[2] = (lg == 0) ? *(const uint2*)(xr + 176)
                                             : make_uint2(0u, 0u);
                Amt[mt] = t.f;
            }
        }
        #pragma unroll
        for (int nt = 0; nt < 6; ++nt) {
            bf16x8 B = ld8(bb + nt * (16 * 192) + kt * 32);
            #pragma unroll
            for (int mt = 0; mt < 4; ++mt)
                acc[nt][mt] = __builtin_amdgcn_mfma_f32_16x16x32_bf16(Amt[mt], B, acc[nt][mt], 0, 0, 0);
        }
    }

    // --- write Q/K (nt 0..3) to LDS transpose buffers; V (nt 4,5) in regs ---
    #pragma unroll
    for (int nt = 0; nt < 4; ++nt) {
        unsigned short* dst = (nt < 2 ? q_s : k_s) + 16 * (nt & 1) + lr;
        #pragma unroll
        for (int mt = 0; mt < 4; ++mt) {
            int row = 16 * mt + 4 * lg;
            dst[(row + 0) * 34] = f2bf(acc[nt][mt][0]);
            dst[(row + 1) * 34] = f2bf(acc[nt][mt][1]);
            dst[(row + 2) * 34] = f2bf(acc[nt][mt][2]);
            dst[(row + 3) * 34] = f2bf(acc[nt][mt][3]);
        }
    }
    unsigned V32[4][2][2];
    #pragma unroll
    for (int j = 0; j < 2; ++j)
        #pragma unroll
        for (int mt = 0; mt < 4; ++mt) {
            V32[mt][j][0] = pk2(acc[4 + j][mt][0], acc[4 + j][mt][1]);
            V32[mt][j][1] = pk2(acc[4 + j][mt][2], acc[4 + j][mt][3]);
        }

    // TBAA pin: u16 ds_writes above vs u32 ds_reads below (round-7 lesson)
    __syncthreads();

    // --- scores^T = mfma(K, Q) ---
    f32x4 s[4][4];
    {
        bf16x8 Bq[4];
        #pragma unroll
        for (int nt = 0; nt < 4; ++nt)
            Bq[nt] = ld8q(q_s + (16 * nt + lr) * 34 + 4 * lg);
        #pragma unroll
        for (int amt = 0; amt < 4; ++amt) {
            bf16x8 Ak = ld8q(k_s + (16 * amt + lr) * 34 + 4 * lg);
            #pragma unroll
            for (int nt = 0; nt < 4; ++nt)
                s[amt][nt] = __builtin_amdgcn_mfma_f32_16x16x32_bf16(
                    Ak, Bq[nt], (f32x4){0.f, 0.f, 0.f, 0.f}, 0, 0, 0);
        }
    }

    // --- in-register softmax + gate ---
    float gsc[4];
    #pragma unroll
    for (int nt = 0; nt < 4; ++nt) {
        float mx = -1e30f;
        #pragma unroll
        for (int amt = 0; amt < 4; ++amt)
            #pragma unroll
            for (int r = 0; r < 4; ++r) mx = fmaxf(mx, s[amt][nt][r]);
        mx = fmaxf(mx, __shfl_xor(mx, 16));
        mx = fmaxf(mx, __shfl_xor(mx, 32));
        float sum = 0.f;
        #pragma unroll
        for (int amt = 0; amt < 4; ++amt)
            #pragma unroll
            for (int r = 0; r < 4; ++r) {
                float p = __expf((s[amt][nt][r] - mx) * 0.18257418583505536f);
                s[amt][nt][r] = p;
                sum += p;
            }
        sum += __shfl_xor(sum, 16);
        sum += __shfl_xor(sum, 32);
        gsc[nt] = vals_g[((long)w * NE + h) * NK + 16 * nt + lr] / sum;
    }

    // --- attn^T = mfma(V^T, P^T); pack as B-fragments ---
    bf16x8 Av[2][2];
    #pragma unroll
    for (int amt = 0; amt < 2; ++amt)
        #pragma unroll
        for (int kt = 0; kt < 2; ++kt) {
            FU t;
            t.u[0] = V32[2 * kt][amt][0];
            t.u[1] = V32[2 * kt][amt][1];
            t.u[2] = V32[2 * kt + 1][amt][0];
            t.u[3] = V32[2 * kt + 1][amt][1];
            Av[amt][kt] = t.f;
        }
    #pragma unroll
    for (int nt = 0; nt < 4; ++nt) {
        bf16x8 Pb[2];
        float g = gsc[nt];
        #pragma unroll
        for (int kt = 0; kt < 2; ++kt) {
            FU t;
            t.u[0] = pk2(s[2 * kt][nt][0] * g, s[2 * kt][nt][1] * g);
            t.u[1] = pk2(s[2 * kt][nt][2] * g, s[2 * kt][nt][3] * g);
            t.u[2] = pk2(s[2 * kt + 1][nt][0] * g, s[2 * kt + 1][nt][1] * g);
            t.u[3] = pk2(s[2 * kt + 1][nt][2] * g, s[2 * kt + 1][nt][3] * g);
            Pb[kt] = t.f;
        }
        f32x4 a0 = (f32x4){0.f, 0.f, 0.f, 0.f};
        a0 = __builtin_amdgcn_mfma_f32_16x16x32_bf16(Av[0][0], Pb[0], a0, 0, 0, 0);
        a0 = __builtin_amdgcn_mfma_f32_16x16x32_bf16(Av[0][1], Pb[1], a0, 0, 0, 0);
        f32x4 a1 = (f32x4){0.f, 0.f, 0.f, 0.f};
        a1 = __builtin_amdgcn_mfma_f32_16x16x32_bf16(Av[1][0], Pb[0], a1, 0, 0, 0);
        a1 = __builtin_amdgcn_mfma_f32_16x16x32_bf16(Av[1][1], Pb[1], a1, 0, 0, 0);
        unsigned short* row = at_g + (((long)h * NWIN + w) * 64 + 16 * nt + lr) * 32;
        *(uint2*)(row + 4 * lg)      = make_uint2(pk2(a0[0], a0[1]), pk2(a0[2], a0[3]));
        *(uint2*)(row + 16 + 4 * lg) = make_uint2(pk2(a1[0], a1[1]), pk2(a1[2], a1[3]));
    }
}

// ---------------------------------------------------------------------------
// k_scatter: ONE block per window; the 4 channel-passes loop INSIDE so the
// at_g B-fragments (48 VGPR) and idx are loaded once instead of 4x.
// Race-free partition per pass (round-14-proven): wave = (nt-half, wcol);
// within one head nt-blocks are row-disjoint, wcol slices col-disjoint;
// per-head __syncthreads() separates cross-head (tok,col) collisions.
// ---------------------------------------------------------------------------
__global__ __launch_bounds__(384) void k_scatter(
    const unsigned short* __restrict__ at_g,
    const unsigned short* __restrict__ Wcomb_t,
    const float* __restrict__ bp,
    const int* __restrict__ idx_g,
    float* __restrict__ out)
{
    __shared__ float outf[256 * 49];
    __shared__ unsigned char idx_s[NE * NK];

    const int w = blockIdx.x;
    const int tid = threadIdx.x;
    const int b = w >> 8, hb = (w >> 4) & 15, wb = w & 15;

    const int wv = tid >> 6;
    const int ln = tid & 63;
    const int lr = ln & 15;
    const int lg = ln >> 4;

    idx_s[tid] = (unsigned char)idx_g[(long)w * NE * NK + tid];  // 384 == NE*NK

    const int wcol = wv % 3;
    const int nth  = wv / 3;            // 0 or 1: nt-blocks {0,1} or {2,3}

    // --- load all B-fragments for this wave's nt-half once (48 VGPR) ---
    bf16x8 Bt[NE][2];
    #pragma unroll
    for (int h = 0; h < NE; ++h)
        #pragma unroll
        for (int t = 0; t < 2; ++t) {
            const int nt = 2 * nth + t;
            Bt[h][t] = ld8(at_g + (((long)h * NWIN + w) * 64 + 16 * nt + lr) * 32 + 4 * lg);
        }
    __syncthreads();   // idx_s visible

    int tokk[NE][2];
    #pragma unroll
    for (int h = 0; h < NE; ++h)
        #pragma unroll
        for (int t = 0; t < 2; ++t)
            tokk[h][t] = idx_s[h * NK + 16 * (2 * nth + t) + lr];

    #pragma unroll 1
    for (int p = 0; p < 4; ++p) {
        for (int f = tid; f < 256 * 49; f += 384) outf[f] = 0.f;
        __syncthreads();

        #pragma unroll 1
        for (int h = 0; h < NE; ++h) {
            bf16x8 Aw = ld8(Wcomb_t + ((long)h * 192 + p * 48 + 16 * wcol + lr) * 32 + 4 * lg);
            #pragma unroll
            for (int t = 0; t < 2; ++t) {
                f32x4 acc = __builtin_amdgcn_mfma_f32_16x16x32_bf16(
                    Aw, Bt[h][t], (f32x4){0.f, 0.f, 0.f, 0.f}, 0, 0, 0);
                float* dst = outf + tokk[h][t] * 49 + 16 * wcol + 4 * lg;
                dst[0] += acc[0];
                dst[1] += acc[1];
                dst[2] += acc[2];
                dst[3] += acc[3];
            }
            __syncthreads();   // separate head intervals (cross-head clashes)
        }

        const int cl2 = (p == 3) ? 18 : 24;  // float2 cols this pass (c<180)
        for (int f = tid; f < 256 * cl2; f += 384) {
            int t = f / cl2, j = f % cl2;
            int c = 48 * p + 2 * j;
            float2 o;
            o.x = outf[t * 49 + 2 * j]     + bp[c];
            o.y = outf[t * 49 + 2 * j + 1] + bp[c + 1];
            long obase = (((long)b * NH + hb * 16 + (t >> 4)) * NW + wb * 16 + (t & 15)) * NC + c;
            *(float2*)(out + obase) = o;
        }
        __syncthreads();   // out-reads of outf done before next pass zeroes
    }
}

// ---------------------------------------------------------------------------
extern "C" void kernel_launch(void* const* d_in, const int* in_sizes, int n_in,
                              void* d_out, int out_size, void* d_ws, size_t ws_size,
                              hipStream_t stream) {
    const float* x    = (const float*)d_in[0];
    const float* Wr   = (const float*)d_in[1];
    const float* Wqkv = (const float*)d_in[2];
    const float* Wo   = (const float*)d_in[3];
    const float* Wp   = (const float*)d_in[4];
    const float* bp   = (const float*)d_in[5];
    float* out = (float*)d_out;

    char* ws = (char*)d_ws;
    unsigned short* Wqkv_t  = (unsigned short*)ws;                  // 221184 B
    unsigned short* Wcomb_t = (unsigned short*)(ws + 221184);       // 73728 B
    int*   idx_g  = (int*)(ws + 294912);                            // 3 MB
    float* vals_g = (float*)(ws + 294912 + (size_t)NWIN * NE * NK * 4);
    unsigned short* at_g = (unsigned short*)(ws + 294912 + 2 * (size_t)NWIN * NE * NK * 4);  // 48 MB
    unsigned short* xbf  = at_g + (size_t)NE * NWIN * 64 * 32;      // 189 MB

    k_prep<<<432, 256, 0, stream>>>(Wqkv, Wo, Wp, Wqkv_t, Wcomb_t);
    k_xbf<<<46080, 256, 0, stream>>>(x, xbf);
    k_router_topk<<<NWIN, 256, 0, stream>>>(x, Wr, idx_g, vals_g);
    k_attn<<<3072, 256, 0, stream>>>(xbf, Wqkv_t, idx_g, vals_g, at_g);
    k_scatter<<<NWIN, 384, 0, stream>>>(at_g, Wcomb_t, bp, idx_g, out);
}

// Round 16
// 687.362 us; speedup vs baseline: 1.1173x; 1.1173x over previous
//
#include <hip/hip_runtime.h>
#include <math.h>

#define NB 8
#define NH 256
#define NW 256
#define NC 180
#define NE 6
#define HD 30
#define NL 256
#define NK 64
#define NWIN 2048

typedef __attribute__((ext_vector_type(8))) short bf16x8;
typedef __attribute__((ext_vector_type(4))) float f32x4;

union FU { bf16x8 f; unsigned u[4]; unsigned short s[8]; };

static __device__ __forceinline__ unsigned short f2bf(float x) {
    unsigned u = __float_as_uint(x);
    unsigned r = (u + 0x7FFFu + ((u >> 16) & 1u)) >> 16;
    return (unsigned short)r;
}
static __device__ __forceinline__ unsigned pk2(float a, float b) {
    return (unsigned)f2bf(a) | ((unsigned)f2bf(b) << 16);
}
// fragment load: elements {p[0..3], p[16..19]} — 8B-aligned rows
static __device__ __forceinline__ bf16x8 ld8(const unsigned short* p) {
    FU t;
    *(uint2*)&t.u[0] = *(const uint2*)p;
    *(uint2*)&t.u[2] = *(const uint2*)(p + 16);
    return t.f;
}
// same element order, 4B-aligned rows (stride-34 LDS)
static __device__ __forceinline__ bf16x8 ld8q(const unsigned short* p) {
    FU t;
    t.u[0] = *(const unsigned*)p;
    t.u[1] = *(const unsigned*)(p + 2);
    t.u[2] = *(const unsigned*)(p + 16);
    t.u[3] = *(const unsigned*)(p + 18);
    return t.f;
}
static __device__ __forceinline__ bf16x8 pack8(float4 a, float4 b) {
    FU t;
    t.u[0] = pk2(a.x, a.y); t.u[1] = pk2(a.z, a.w);
    t.u[2] = pk2(b.x, b.y); t.u[3] = pk2(b.z, b.w);
    return t.f;
}

// ---------------------------------------------------------------------------
// prep: Wqkv_t[h][n'<96][k<192] (n' = sec*32+r, n = sec*30+r; pads zero)
//       Wcomb_t[h][o<192][d<32] = (Wo[h] @ Wp^T)^T  (pads zero)
// ---------------------------------------------------------------------------
__global__ __launch_bounds__(256) void k_prep(
    const float* __restrict__ Wqkv, const float* __restrict__ Wo,
    const float* __restrict__ Wp,
    unsigned short* __restrict__ Wqkv_t, unsigned short* __restrict__ Wcomb_t)
{
    int i = blockIdx.x * 256 + threadIdx.x;
    if (i < NE * 96 * 192) {
        int h = i / (96 * 192), rm = i % (96 * 192), np = rm / 192, k = rm % 192;
        int sec = np >> 5, r = np & 31;
        float v = (r < 30 && k < NC) ? Wqkv[((long)h * NC + k) * 90 + sec * 30 + r] : 0.f;
        Wqkv_t[i] = f2bf(v);
    }
    if (i < NE * 192 * 32) {
        int h = i / (192 * 32), rm = i % (192 * 32), o = rm / 32, d = rm & 31;
        float acc = 0.f;
        if (o < NC && d < HD) {
            const float* wo = Wo + ((long)h * HD + d) * NC;
            const float* wp = Wp + (long)o * NC;
            for (int c = 0; c < NC; ++c) acc += wo[c] * wp[c];
        }
        Wcomb_t[i] = f2bf(acc);
    }
}

// ---------------------------------------------------------------------------
// Router: staging + logit + sigmoid phases VERBATIM from round 1 (those
// compiled float bits match the np reference's selection exactly — do not
// touch). Selection: exact bitonic sort on sigmoid bits (round-13-proven).
// ---------------------------------------------------------------------------
__global__ __launch_bounds__(256) void k_router_topk(
    const float* __restrict__ x, const float* __restrict__ Wr,
    int* __restrict__ idx_g, float* __restrict__ vals_g)
{
    __shared__ float wr_s[NE * NC];
    __shared__ __align__(16) float xs[32 * 181];   // overlaid by keys after logits
    __shared__ float lg[NE * NL];

    const int w   = blockIdx.x;
    const int tid = threadIdx.x;
    const int b = w >> 8, hb = (w >> 4) & 15, wb = w & 15;
    const long win_base = (((long)b * NH + hb * 16) * NW + wb * 16) * NC;

    for (int f = tid; f < NE * NC; f += 256) wr_s[f] = Wr[f];
    __syncthreads();

    for (int tile = 0; tile < 8; ++tile) {
        for (int f = tid; f < 32 * NC; f += 256) {
            int tl = f / NC, ch = f % NC;
            int tok = tile * 32 + tl;
            int r = tok >> 4, cl = tok & 15;
            xs[tl * 181 + ch] = x[win_base + ((long)r * NW + cl) * NC + ch];
        }
        __syncthreads();
        if (tid < 192) {
            int tl = tid & 31, e = tid >> 5;
            float acc = 0.f;
            for (int c = 0; c < NC; ++c) acc += xs[tl * 181 + c] * wr_s[e * NC + c];
            lg[e * NL + tile * 32 + tl] = 1.0f / (1.0f + expf(-acc));
        }
        __syncthreads();
    }

    // ---- exact top-63 via bitonic sort of composite keys (bits identical) --
    unsigned long long* keys = (unsigned long long*)xs;  // xs dead; barriers pin
    #pragma unroll
    for (int e = 0; e < NE; ++e) {
        unsigned kb = __float_as_uint(lg[e * NL + tid]);
        unsigned long long comp =
            ((unsigned long long)kb << 32) | (unsigned)(0xFFFFFFFFu - tid);
        if (tid == 0) comp = 0ull;   // token 0 excluded from ranked list
        keys[e * NL + tid] = comp;
    }
    __syncthreads();

    for (int k = 2; k <= 256; k <<= 1) {
        for (int j = k >> 1; j > 0; j >>= 1) {
            const int i = tid, ixj = i ^ j;
            if (ixj > i) {
                const bool up = ((i & k) == 0);
                #pragma unroll
                for (int e = 0; e < NE; ++e) {
                    unsigned long long a  = keys[e * NL + i];
                    unsigned long long bv = keys[e * NL + ixj];
                    bool sw = up ? (a < bv) : (a > bv);   // descending sort
                    if (sw) { keys[e * NL + i] = bv; keys[e * NL + ixj] = a; }
                }
            }
            __syncthreads();
        }
    }

    if (tid < NK - 1) {   // sorted position == rank; slots 1..63
        #pragma unroll
        for (int e = 0; e < NE; ++e) {
            unsigned long long kk = keys[e * NL + tid];
            int t = (int)(0xFFFFFFFFu - (unsigned)kk);
            idx_g[(w * NE + e) * NK + 1 + tid]  = t;
            vals_g[(w * NE + e) * NK + 1 + tid] = __uint_as_float((unsigned)(kk >> 32));
        }
    }
    if (tid == 0) {
        #pragma unroll
        for (int e = 0; e < NE; ++e) {
            idx_g[(w * NE + e) * NK]  = 0;
            vals_g[(w * NE + e) * NK] = lg[e * NL];
        }
    }
}

// ---------------------------------------------------------------------------
// k_attn: one WAVE per (window, head), w-major. VERBATIM round 14 (fp32 x).
//   at_g[(h*2048 + w)*64 + slot][32] bf16  (cols 30,31 zero-pad)
// ---------------------------------------------------------------------------
__global__ __launch_bounds__(256, 3) void k_attn(
    const float* __restrict__ x,
    const unsigned short* __restrict__ Wqkv_t,
    const int* __restrict__ idx_g, const float* __restrict__ vals_g,
    unsigned short* __restrict__ at_g)
{
    __shared__ char sm[34816];
    const int tid = threadIdx.x;
    const int wv = tid >> 6;
    const int ln = tid & 63;
    const int lr = ln & 15;
    const int lg = ln >> 4;

    const int id = blockIdx.x * 4 + wv;      // w-major: id = w*6 + h
    const int w = id / 6;
    const int h = id % 6;
    const int b = w >> 8, hb = (w >> 4) & 15, wb = w & 15;
    const long win_base = (((long)b * NH + hb * 16) * NW + wb * 16) * NC;

    unsigned short* q_s = (unsigned short*)(sm + wv * 8704);
    unsigned short* k_s = q_s + 2176;

    int tokr[4];
    #pragma unroll
    for (int t = 0; t < 4; ++t)
        tokr[t] = idx_g[((long)w * NE + h) * NK + 16 * t + lr];

    // --- QKV = gather(x) @ Wqkv_t : M=64, N=96, K=192 ---
    f32x4 acc[6][4];
    #pragma unroll
    for (int nt = 0; nt < 6; ++nt)
        #pragma unroll
        for (int mt = 0; mt < 4; ++mt) acc[nt][mt] = (f32x4){0.f, 0.f, 0.f, 0.f};

    const unsigned short* bb = Wqkv_t + ((long)h * 96 + lr) * 192 + 4 * lg;
    #pragma unroll
    for (int kt = 0; kt < 6; ++kt) {
        bf16x8 Amt[4];
        #pragma unroll
        for (int mt = 0; mt < 4; ++mt) {
            const float* xr = x + win_base +
                ((long)(tokr[mt] >> 4) * NW + (tokr[mt] & 15)) * NC;
            if (kt < 5) {
                float4 a  = *(const float4*)(xr + 4 * lg + 32 * kt);
                float4 b2 = *(const float4*)(xr + 4 * lg + 32 * kt + 16);
                Amt[mt] = pack8(a, b2);
            } else {
                float4 a  = *(const float4*)(xr + 4 * lg + 160);
                float4 b2 = make_float4(0.f, 0.f, 0.f, 0.f);
                if (lg == 0) b2 = *(const float4*)(xr + 176);
                Amt[mt] = pack8(a, b2);
            }
        }
        #pragma unroll
        for (int nt = 0; nt < 6; ++nt) {
            bf16x8 B = ld8(bb + nt * (16 * 192) + kt * 32);
            #pragma unroll
            for (int mt = 0; mt < 4; ++mt)
                acc[nt][mt] = __builtin_amdgcn_mfma_f32_16x16x32_bf16(Amt[mt], B, acc[nt][mt], 0, 0, 0);
        }
    }

    // --- write Q/K (nt 0..3) to LDS transpose buffers; V (nt 4,5) in regs ---
    #pragma unroll
    for (int nt = 0; nt < 4; ++nt) {
        unsigned short* dst = (nt < 2 ? q_s : k_s) + 16 * (nt & 1) + lr;
        #pragma unroll
        for (int mt = 0; mt < 4; ++mt) {
            int row = 16 * mt + 4 * lg;
            dst[(row + 0) * 34] = f2bf(acc[nt][mt][0]);
            dst[(row + 1) * 34] = f2bf(acc[nt][mt][1]);
            dst[(row + 2) * 34] = f2bf(acc[nt][mt][2]);
            dst[(row + 3) * 34] = f2bf(acc[nt][mt][3]);
        }
    }
    unsigned V32[4][2][2];
    #pragma unroll
    for (int j = 0; j < 2; ++j)
        #pragma unroll
        for (int mt = 0; mt < 4; ++mt) {
            V32[mt][j][0] = pk2(acc[4 + j][mt][0], acc[4 + j][mt][1]);
            V32[mt][j][1] = pk2(acc[4 + j][mt][2], acc[4 + j][mt][3]);
        }

    // TBAA pin: u16 ds_writes above vs u32 ds_reads below (round-7 lesson)
    __syncthreads();

    // --- scores^T = mfma(K, Q) ---
    f32x4 s[4][4];
    {
        bf16x8 Bq[4];
        #pragma unroll
        for (int nt = 0; nt < 4; ++nt)
            Bq[nt] = ld8q(q_s + (16 * nt + lr) * 34 + 4 * lg);
        #pragma unroll
        for (int amt = 0; amt < 4; ++amt) {
            bf16x8 Ak = ld8q(k_s + (16 * amt + lr) * 34 + 4 * lg);
            #pragma unroll
            for (int nt = 0; nt < 4; ++nt)
                s[amt][nt] = __builtin_amdgcn_mfma_f32_16x16x32_bf16(
                    Ak, Bq[nt], (f32x4){0.f, 0.f, 0.f, 0.f}, 0, 0, 0);
        }
    }

    // --- in-register softmax + gate ---
    float gsc[4];
    #pragma unroll
    for (int nt = 0; nt < 4; ++nt) {
        float mx = -1e30f;
        #pragma unroll
        for (int amt = 0; amt < 4; ++amt)
            #pragma unroll
            for (int r = 0; r < 4; ++r) mx = fmaxf(mx, s[amt][nt][r]);
        mx = fmaxf(mx, __shfl_xor(mx, 16));
        mx = fmaxf(mx, __shfl_xor(mx, 32));
        float sum = 0.f;
        #pragma unroll
        for (int amt = 0; amt < 4; ++amt)
            #pragma unroll
            for (int r = 0; r < 4; ++r) {
                float p = __expf((s[amt][nt][r] - mx) * 0.18257418583505536f);
                s[amt][nt][r] = p;
                sum += p;
            }
        sum += __shfl_xor(sum, 16);
        sum += __shfl_xor(sum, 32);
        gsc[nt] = vals_g[((long)w * NE + h) * NK + 16 * nt + lr] / sum;
    }

    // --- attn^T = mfma(V^T, P^T); pack as B-fragments ---
    bf16x8 Av[2][2];
    #pragma unroll
    for (int amt = 0; amt < 2; ++amt)
        #pragma unroll
        for (int kt = 0; kt < 2; ++kt) {
            FU t;
            t.u[0] = V32[2 * kt][amt][0];
            t.u[1] = V32[2 * kt][amt][1];
            t.u[2] = V32[2 * kt + 1][amt][0];
            t.u[3] = V32[2 * kt + 1][amt][1];
            Av[amt][kt] = t.f;
        }
    #pragma unroll
    for (int nt = 0; nt < 4; ++nt) {
        bf16x8 Pb[2];
        float g = gsc[nt];
        #pragma unroll
        for (int kt = 0; kt < 2; ++kt) {
            FU t;
            t.u[0] = pk2(s[2 * kt][nt][0] * g, s[2 * kt][nt][1] * g);
            t.u[1] = pk2(s[2 * kt][nt][2] * g, s[2 * kt][nt][3] * g);
            t.u[2] = pk2(s[2 * kt + 1][nt][0] * g, s[2 * kt + 1][nt][1] * g);
            t.u[3] = pk2(s[2 * kt + 1][nt][2] * g, s[2 * kt + 1][nt][3] * g);
            Pb[kt] = t.f;
        }
        f32x4 a0 = (f32x4){0.f, 0.f, 0.f, 0.f};
        a0 = __builtin_amdgcn_mfma_f32_16x16x32_bf16(Av[0][0], Pb[0], a0, 0, 0, 0);
        a0 = __builtin_amdgcn_mfma_f32_16x16x32_bf16(Av[0][1], Pb[1], a0, 0, 0, 0);
        f32x4 a1 = (f32x4){0.f, 0.f, 0.f, 0.f};
        a1 = __builtin_amdgcn_mfma_f32_16x16x32_bf16(Av[1][0], Pb[0], a1, 0, 0, 0);
        a1 = __builtin_amdgcn_mfma_f32_16x16x32_bf16(Av[1][1], Pb[1], a1, 0, 0, 0);
        unsigned short* row = at_g + (((long)h * NWIN + w) * 64 + 16 * nt + lr) * 32;
        *(uint2*)(row + 4 * lg)      = make_uint2(pk2(a0[0], a0[1]), pk2(a0[2], a0[3]));
        *(uint2*)(row + 16 + 4 * lg) = make_uint2(pk2(a1[0], a1[1]), pk2(a1[2], a1[3]));
    }
}

// ---------------------------------------------------------------------------
// k_scatter: ONE block per window, 4 channel-passes inside (Bt/idx loaded
// once). __launch_bounds__(384, 2): 256-VGPR budget keeps Bt[6][2] (48 regs)
// in registers — round 15's default budget spilled them (+173 MB scratch).
// Race-free partition per pass (round-14-proven): wave = (nt-half, wcol);
// within one head nt-blocks are row-disjoint, wcol slices col-disjoint;
// per-head __syncthreads() separates cross-head (tok,col) collisions.
// float4 out-writes (both sides 16B-aligned: token base 720 B, c % 4 == 0).
// ---------------------------------------------------------------------------
__global__ __launch_bounds__(384, 2) void k_scatter(
    const unsigned short* __restrict__ at_g,
    const unsigned short* __restrict__ Wcomb_t,
    const float* __restrict__ bp,
    const int* __restrict__ idx_g,
    float* __restrict__ out)
{
    __shared__ float outf[256 * 49];
    __shared__ unsigned char idx_s[NE * NK];

    const int w = blockIdx.x;
    const int tid = threadIdx.x;
    const int b = w >> 8, hb = (w >> 4) & 15, wb = w & 15;

    const int wv = tid >> 6;
    const int ln = tid & 63;
    const int lr = ln & 15;
    const int lg = ln >> 4;

    idx_s[tid] = (unsigned char)idx_g[(long)w * NE * NK + tid];  // 384 == NE*NK

    const int wcol = wv % 3;
    const int nth  = wv / 3;            // 0 or 1: nt-blocks {0,1} or {2,3}

    // --- load all B-fragments for this wave's nt-half once (48 VGPR) ---
    bf16x8 Bt[NE][2];
    #pragma unroll
    for (int h = 0; h < NE; ++h)
        #pragma unroll
        for (int t = 0; t < 2; ++t) {
            const int nt = 2 * nth + t;
            Bt[h][t] = ld8(at_g + (((long)h * NWIN + w) * 64 + 16 * nt + lr) * 32 + 4 * lg);
        }
    __syncthreads();   // idx_s visible

    int tokk[NE][2];
    #pragma unroll
    for (int h = 0; h < NE; ++h)
        #pragma unroll
        for (int t = 0; t < 2; ++t)
            tokk[h][t] = idx_s[h * NK + 16 * (2 * nth + t) + lr];

    #pragma unroll 1
    for (int p = 0; p < 4; ++p) {
        for (int f = tid; f < 256 * 49; f += 384) outf[f] = 0.f;
        __syncthreads();

        #pragma unroll 1
        for (int h = 0; h < NE; ++h) {
            bf16x8 Aw = ld8(Wcomb_t + ((long)h * 192 + p * 48 + 16 * wcol + lr) * 32 + 4 * lg);
            #pragma unroll
            for (int t = 0; t < 2; ++t) {
                f32x4 acc = __builtin_amdgcn_mfma_f32_16x16x32_bf16(
                    Aw, Bt[h][t], (f32x4){0.f, 0.f, 0.f, 0.f}, 0, 0, 0);
                float* dst = outf + tokk[h][t] * 49 + 16 * wcol + 4 * lg;
                dst[0] += acc[0];
                dst[1] += acc[1];
                dst[2] += acc[2];
                dst[3] += acc[3];
            }
            __syncthreads();   // separate head intervals (cross-head clashes)
        }

        const int nf4 = (p == 3) ? 9 : 12;   // float4 cols this pass (c<180)
        for (int f = tid; f < 256 * nf4; f += 384) {
            int t = f / nf4, j = f % nf4;
            int c = 48 * p + 4 * j;
            float4 o;
            o.x = outf[t * 49 + 4 * j]     + bp[c];
            o.y = outf[t * 49 + 4 * j + 1] + bp[c + 1];
            o.z = outf[t * 49 + 4 * j + 2] + bp[c + 2];
            o.w = outf[t * 49 + 4 * j + 3] + bp[c + 3];
            long obase = (((long)b * NH + hb * 16 + (t >> 4)) * NW + wb * 16 + (t & 15)) * NC + c;
            *(float4*)(out + obase) = o;
        }
        __syncthreads();   // out-reads of outf done before next pass zeroes
    }
}

// ---------------------------------------------------------------------------
extern "C" void kernel_launch(void* const* d_in, const int* in_sizes, int n_in,
                              void* d_out, int out_size, void* d_ws, size_t ws_size,
                              hipStream_t stream) {
    const float* x    = (const float*)d_in[0];
    const float* Wr   = (const float*)d_in[1];
    const float* Wqkv = (const float*)d_in[2];
    const float* Wo   = (const float*)d_in[3];
    const float* Wp   = (const float*)d_in[4];
    const float* bp   = (const float*)d_in[5];
    float* out = (float*)d_out;

    char* ws = (char*)d_ws;
    unsigned short* Wqkv_t  = (unsigned short*)ws;                  // 221184 B
    unsigned short* Wcomb_t = (unsigned short*)(ws + 221184);       // 73728 B
    int*   idx_g  = (int*)(ws + 294912);                            // 3 MB
    float* vals_g = (float*)(ws + 294912 + (size_t)NWIN * NE * NK * 4);
    unsigned short* at_g = (unsigned short*)(ws + 294912 + 2 * (size_t)NWIN * NE * NK * 4);  // 48 MB

    k_prep<<<432, 256, 0, stream>>>(Wqkv, Wo, Wp, Wqkv_t, Wcomb_t);
    k_router_topk<<<NWIN, 256, 0, stream>>>(x, Wr, idx_g, vals_g);
    k_attn<<<3072, 256, 0, stream>>>(x, Wqkv_t, idx_g, vals_g, at_g);
    k_scatter<<<NWIN, 384, 0, stream>>>(at_g, Wcomb_t, bp, idx_g, out);
}

// Round 17
// 598.546 us; speedup vs baseline: 1.2831x; 1.1484x over previous
//
#include <hip/hip_runtime.h>
#include <math.h>

#define NB 8
#define NH 256
#define NW 256
#define NC 180
#define NE 6
#define HD 30
#define NL 256
#define NK 64
#define NWIN 2048

typedef __attribute__((ext_vector_type(8))) short bf16x8;
typedef __attribute__((ext_vector_type(4))) float f32x4;

union FU { bf16x8 f; unsigned u[4]; unsigned short s[8]; };

static __device__ __forceinline__ unsigned short f2bf(float x) {
    unsigned u = __float_as_uint(x);
    unsigned r = (u + 0x7FFFu + ((u >> 16) & 1u)) >> 16;
    return (unsigned short)r;
}
static __device__ __forceinline__ unsigned pk2(float a, float b) {
    return (unsigned)f2bf(a) | ((unsigned)f2bf(b) << 16);
}
// fragment load: elements {p[0..3], p[16..19]} — 8B-aligned rows
static __device__ __forceinline__ bf16x8 ld8(const unsigned short* p) {
    FU t;
    *(uint2*)&t.u[0] = *(const uint2*)p;
    *(uint2*)&t.u[2] = *(const uint2*)(p + 16);
    return t.f;
}
// same element order, 4B-aligned rows (stride-34 LDS)
static __device__ __forceinline__ bf16x8 ld8q(const unsigned short* p) {
    FU t;
    t.u[0] = *(const unsigned*)p;
    t.u[1] = *(const unsigned*)(p + 2);
    t.u[2] = *(const unsigned*)(p + 16);
    t.u[3] = *(const unsigned*)(p + 18);
    return t.f;
}
static __device__ __forceinline__ bf16x8 pack8(float4 a, float4 b) {
    FU t;
    t.u[0] = pk2(a.x, a.y); t.u[1] = pk2(a.z, a.w);
    t.u[2] = pk2(b.x, b.y); t.u[3] = pk2(b.z, b.w);
    return t.f;
}

// ---------------------------------------------------------------------------
// prep: Wqkv_t[h][n'<96][k<192] (n' = sec*32+r, n = sec*30+r; pads zero)
//       Wcomb_t[h][o<192][d<32] = (Wo[h] @ Wp^T)^T  (pads zero)
// ---------------------------------------------------------------------------
__global__ __launch_bounds__(256) void k_prep(
    const float* __restrict__ Wqkv, const float* __restrict__ Wo,
    const float* __restrict__ Wp,
    unsigned short* __restrict__ Wqkv_t, unsigned short* __restrict__ Wcomb_t)
{
    int i = blockIdx.x * 256 + threadIdx.x;
    if (i < NE * 96 * 192) {
        int h = i / (96 * 192), rm = i % (96 * 192), np = rm / 192, k = rm % 192;
        int sec = np >> 5, r = np & 31;
        float v = (r < 30 && k < NC) ? Wqkv[((long)h * NC + k) * 90 + sec * 30 + r] : 0.f;
        Wqkv_t[i] = f2bf(v);
    }
    if (i < NE * 192 * 32) {
        int h = i / (192 * 32), rm = i % (192 * 32), o = rm / 32, d = rm & 31;
        float acc = 0.f;
        if (o < NC && d < HD) {
            const float* wo = Wo + ((long)h * HD + d) * NC;
            const float* wp = Wp + (long)o * NC;
            for (int c = 0; c < NC; ++c) acc += wo[c] * wp[c];
        }
        Wcomb_t[i] = f2bf(acc);
    }
}

// ---------------------------------------------------------------------------
// Router: staging + logit + sigmoid phases VERBATIM from round 1 (those
// compiled float bits match the np reference's selection exactly — do not
// touch). Selection: exact bitonic sort on sigmoid bits (round-13-proven).
// ---------------------------------------------------------------------------
__global__ __launch_bounds__(256) void k_router_topk(
    const float* __restrict__ x, const float* __restrict__ Wr,
    int* __restrict__ idx_g, float* __restrict__ vals_g)
{
    __shared__ float wr_s[NE * NC];
    __shared__ __align__(16) float xs[32 * 181];   // overlaid by keys after logits
    __shared__ float lg[NE * NL];

    const int w   = blockIdx.x;
    const int tid = threadIdx.x;
    const int b = w >> 8, hb = (w >> 4) & 15, wb = w & 15;
    const long win_base = (((long)b * NH + hb * 16) * NW + wb * 16) * NC;

    for (int f = tid; f < NE * NC; f += 256) wr_s[f] = Wr[f];
    __syncthreads();

    for (int tile = 0; tile < 8; ++tile) {
        for (int f = tid; f < 32 * NC; f += 256) {
            int tl = f / NC, ch = f % NC;
            int tok = tile * 32 + tl;
            int r = tok >> 4, cl = tok & 15;
            xs[tl * 181 + ch] = x[win_base + ((long)r * NW + cl) * NC + ch];
        }
        __syncthreads();
        if (tid < 192) {
            int tl = tid & 31, e = tid >> 5;
            float acc = 0.f;
            for (int c = 0; c < NC; ++c) acc += xs[tl * 181 + c] * wr_s[e * NC + c];
            lg[e * NL + tile * 32 + tl] = 1.0f / (1.0f + expf(-acc));
        }
        __syncthreads();
    }

    // ---- exact top-63 via bitonic sort of composite keys (bits identical) --
    unsigned long long* keys = (unsigned long long*)xs;  // xs dead; barriers pin
    #pragma unroll
    for (int e = 0; e < NE; ++e) {
        unsigned kb = __float_as_uint(lg[e * NL + tid]);
        unsigned long long comp =
            ((unsigned long long)kb << 32) | (unsigned)(0xFFFFFFFFu - tid);
        if (tid == 0) comp = 0ull;   // token 0 excluded from ranked list
        keys[e * NL + tid] = comp;
    }
    __syncthreads();

    for (int k = 2; k <= 256; k <<= 1) {
        for (int j = k >> 1; j > 0; j >>= 1) {
            const int i = tid, ixj = i ^ j;
            if (ixj > i) {
                const bool up = ((i & k) == 0);
                #pragma unroll
                for (int e = 0; e < NE; ++e) {
                    unsigned long long a  = keys[e * NL + i];
                    unsigned long long bv = keys[e * NL + ixj];
                    bool sw = up ? (a < bv) : (a > bv);   // descending sort
                    if (sw) { keys[e * NL + i] = bv; keys[e * NL + ixj] = a; }
                }
            }
            __syncthreads();
        }
    }

    if (tid < NK - 1) {   // sorted position == rank; slots 1..63
        #pragma unroll
        for (int e = 0; e < NE; ++e) {
            unsigned long long kk = keys[e * NL + tid];
            int t = (int)(0xFFFFFFFFu - (unsigned)kk);
            idx_g[(w * NE + e) * NK + 1 + tid]  = t;
            vals_g[(w * NE + e) * NK + 1 + tid] = __uint_as_float((unsigned)(kk >> 32));
        }
    }
    if (tid == 0) {
        #pragma unroll
        for (int e = 0; e < NE; ++e) {
            idx_g[(w * NE + e) * NK]  = 0;
            vals_g[(w * NE + e) * NK] = lg[e * NL];
        }
    }
}

// ---------------------------------------------------------------------------
// k_attn: one WAVE per (window, head), w-major. VERBATIM round 14 (fp32 x).
//   at_g[(h*2048 + w)*64 + slot][32] bf16  (cols 30,31 zero-pad)
// ---------------------------------------------------------------------------
__global__ __launch_bounds__(256, 3) void k_attn(
    const float* __restrict__ x,
    const unsigned short* __restrict__ Wqkv_t,
    const int* __restrict__ idx_g, const float* __restrict__ vals_g,
    unsigned short* __restrict__ at_g)
{
    __shared__ char sm[34816];
    const int tid = threadIdx.x;
    const int wv = tid >> 6;
    const int ln = tid & 63;
    const int lr = ln & 15;
    const int lg = ln >> 4;

    const int id = blockIdx.x * 4 + wv;      // w-major: id = w*6 + h
    const int w = id / 6;
    const int h = id % 6;
    const int b = w >> 8, hb = (w >> 4) & 15, wb = w & 15;
    const long win_base = (((long)b * NH + hb * 16) * NW + wb * 16) * NC;

    unsigned short* q_s = (unsigned short*)(sm + wv * 8704);
    unsigned short* k_s = q_s + 2176;

    int tokr[4];
    #pragma unroll
    for (int t = 0; t < 4; ++t)
        tokr[t] = idx_g[((long)w * NE + h) * NK + 16 * t + lr];

    // --- QKV = gather(x) @ Wqkv_t : M=64, N=96, K=192 ---
    f32x4 acc[6][4];
    #pragma unroll
    for (int nt = 0; nt < 6; ++nt)
        #pragma unroll
        for (int mt = 0; mt < 4; ++mt) acc[nt][mt] = (f32x4){0.f, 0.f, 0.f, 0.f};

    const unsigned short* bb = Wqkv_t + ((long)h * 96 + lr) * 192 + 4 * lg;
    #pragma unroll
    for (int kt = 0; kt < 6; ++kt) {
        bf16x8 Amt[4];
        #pragma unroll
        for (int mt = 0; mt < 4; ++mt) {
            const float* xr = x + win_base +
                ((long)(tokr[mt] >> 4) * NW + (tokr[mt] & 15)) * NC;
            if (kt < 5) {
                float4 a  = *(const float4*)(xr + 4 * lg + 32 * kt);
                float4 b2 = *(const float4*)(xr + 4 * lg + 32 * kt + 16);
                Amt[mt] = pack8(a, b2);
            } else {
                float4 a  = *(const float4*)(xr + 4 * lg + 160);
                float4 b2 = make_float4(0.f, 0.f, 0.f, 0.f);
                if (lg == 0) b2 = *(const float4*)(xr + 176);
                Amt[mt] = pack8(a, b2);
            }
        }
        #pragma unroll
        for (int nt = 0; nt < 6; ++nt) {
            bf16x8 B = ld8(bb + nt * (16 * 192) + kt * 32);
            #pragma unroll
            for (int mt = 0; mt < 4; ++mt)
                acc[nt][mt] = __builtin_amdgcn_mfma_f32_16x16x32_bf16(Amt[mt], B, acc[nt][mt], 0, 0, 0);
        }
    }

    // --- write Q/K (nt 0..3) to LDS transpose buffers; V (nt 4,5) in regs ---
    #pragma unroll
    for (int nt = 0; nt < 4; ++nt) {
        unsigned short* dst = (nt < 2 ? q_s : k_s) + 16 * (nt & 1) + lr;
        #pragma unroll
        for (int mt = 0; mt < 4; ++mt) {
            int row = 16 * mt + 4 * lg;
            dst[(row + 0) * 34] = f2bf(acc[nt][mt][0]);
            dst[(row + 1) * 34] = f2bf(acc[nt][mt][1]);
            dst[(row + 2) * 34] = f2bf(acc[nt][mt][2]);
            dst[(row + 3) * 34] = f2bf(acc[nt][mt][3]);
        }
    }
    unsigned V32[4][2][2];
    #pragma unroll
    for (int j = 0; j < 2; ++j)
        #pragma unroll
        for (int mt = 0; mt < 4; ++mt) {
            V32[mt][j][0] = pk2(acc[4 + j][mt][0], acc[4 + j][mt][1]);
            V32[mt][j][1] = pk2(acc[4 + j][mt][2], acc[4 + j][mt][3]);
        }

    // TBAA pin: u16 ds_writes above vs u32 ds_reads below (round-7 lesson)
    __syncthreads();

    // --- scores^T = mfma(K, Q) ---
    f32x4 s[4][4];
    {
        bf16x8 Bq[4];
        #pragma unroll
        for (int nt = 0; nt < 4; ++nt)
            Bq[nt] = ld8q(q_s + (16 * nt + lr) * 34 + 4 * lg);
        #pragma unroll
        for (int amt = 0; amt < 4; ++amt) {
            bf16x8 Ak = ld8q(k_s + (16 * amt + lr) * 34 + 4 * lg);
            #pragma unroll
            for (int nt = 0; nt < 4; ++nt)
                s[amt][nt] = __builtin_amdgcn_mfma_f32_16x16x32_bf16(
                    Ak, Bq[nt], (f32x4){0.f, 0.f, 0.f, 0.f}, 0, 0, 0);
        }
    }

    // --- in-register softmax + gate ---
    float gsc[4];
    #pragma unroll
    for (int nt = 0; nt < 4; ++nt) {
        float mx = -1e30f;
        #pragma unroll
        for (int amt = 0; amt < 4; ++amt)
            #pragma unroll
            for (int r = 0; r < 4; ++r) mx = fmaxf(mx, s[amt][nt][r]);
        mx = fmaxf(mx, __shfl_xor(mx, 16));
        mx = fmaxf(mx, __shfl_xor(mx, 32));
        float sum = 0.f;
        #pragma unroll
        for (int amt = 0; amt < 4; ++amt)
            #pragma unroll
            for (int r = 0; r < 4; ++r) {
                float p = __expf((s[amt][nt][r] - mx) * 0.18257418583505536f);
                s[amt][nt][r] = p;
                sum += p;
            }
        sum += __shfl_xor(sum, 16);
        sum += __shfl_xor(sum, 32);
        gsc[nt] = vals_g[((long)w * NE + h) * NK + 16 * nt + lr] / sum;
    }

    // --- attn^T = mfma(V^T, P^T); pack as B-fragments ---
    bf16x8 Av[2][2];
    #pragma unroll
    for (int amt = 0; amt < 2; ++amt)
        #pragma unroll
        for (int kt = 0; kt < 2; ++kt) {
            FU t;
            t.u[0] = V32[2 * kt][amt][0];
            t.u[1] = V32[2 * kt][amt][1];
            t.u[2] = V32[2 * kt + 1][amt][0];
            t.u[3] = V32[2 * kt + 1][amt][1];
            Av[amt][kt] = t.f;
        }
    #pragma unroll
    for (int nt = 0; nt < 4; ++nt) {
        bf16x8 Pb[2];
        float g = gsc[nt];
        #pragma unroll
        for (int kt = 0; kt < 2; ++kt) {
            FU t;
            t.u[0] = pk2(s[2 * kt][nt][0] * g, s[2 * kt][nt][1] * g);
            t.u[1] = pk2(s[2 * kt][nt][2] * g, s[2 * kt][nt][3] * g);
            t.u[2] = pk2(s[2 * kt + 1][nt][0] * g, s[2 * kt + 1][nt][1] * g);
            t.u[3] = pk2(s[2 * kt + 1][nt][2] * g, s[2 * kt + 1][nt][3] * g);
            Pb[kt] = t.f;
        }
        f32x4 a0 = (f32x4){0.f, 0.f, 0.f, 0.f};
        a0 = __builtin_amdgcn_mfma_f32_16x16x32_bf16(Av[0][0], Pb[0], a0, 0, 0, 0);
        a0 = __builtin_amdgcn_mfma_f32_16x16x32_bf16(Av[0][1], Pb[1], a0, 0, 0, 0);
        f32x4 a1 = (f32x4){0.f, 0.f, 0.f, 0.f};
        a1 = __builtin_amdgcn_mfma_f32_16x16x32_bf16(Av[1][0], Pb[0], a1, 0, 0, 0);
        a1 = __builtin_amdgcn_mfma_f32_16x16x32_bf16(Av[1][1], Pb[1], a1, 0, 0, 0);
        unsigned short* row = at_g + (((long)h * NWIN + w) * 64 + 16 * nt + lr) * 32;
        *(uint2*)(row + 4 * lg)      = make_uint2(pk2(a0[0], a0[1]), pk2(a0[2], a0[3]));
        *(uint2*)(row + 16 + 4 * lg) = make_uint2(pk2(a1[0], a1[1]), pk2(a1[2], a1[3]));
    }
}

// ---------------------------------------------------------------------------
// k_scatter: ONE block per window, 4 channel-passes inside (Bt/idx loaded
// once). ALL register arrays statically indexed (FULL unroll of h and p
// loops) — rounds 15/16 spilled 173 MB because Bt[h][t] with runtime h goes
// to scratch no matter the VGPR budget (rule #20).
// Race-free partition per pass (round-14-proven): wave = (nt-half, wcol);
// within one head nt-blocks are row-disjoint, wcol slices col-disjoint;
// per-head __syncthreads() separates cross-head (tok,col) collisions.
// float4 out-writes (both sides 16B-aligned: token base 720 B, c % 4 == 0).
// ---------------------------------------------------------------------------
__global__ __launch_bounds__(384, 2) void k_scatter(
    const unsigned short* __restrict__ at_g,
    const unsigned short* __restrict__ Wcomb_t,
    const float* __restrict__ bp,
    const int* __restrict__ idx_g,
    float* __restrict__ out)
{
    __shared__ float outf[256 * 49];
    __shared__ unsigned char idx_s[NE * NK];

    const int w = blockIdx.x;
    const int tid = threadIdx.x;
    const int b = w >> 8, hb = (w >> 4) & 15, wb = w & 15;

    const int wv = tid >> 6;
    const int ln = tid & 63;
    const int lr = ln & 15;
    const int lg = ln >> 4;

    idx_s[tid] = (unsigned char)idx_g[(long)w * NE * NK + tid];  // 384 == NE*NK

    const int wcol = wv % 3;
    const int nth  = wv / 3;            // 0 or 1: nt-blocks {0,1} or {2,3}

    // --- load all B-fragments for this wave's nt-half once (48 VGPR) ---
    bf16x8 Bt[NE][2];
    #pragma unroll
    for (int h = 0; h < NE; ++h)
        #pragma unroll
        for (int t = 0; t < 2; ++t) {
            const int nt = 2 * nth + t;
            Bt[h][t] = ld8(at_g + (((long)h * NWIN + w) * 64 + 16 * nt + lr) * 32 + 4 * lg);
        }
    __syncthreads();   // idx_s visible

    int tokk[NE][2];
    #pragma unroll
    for (int h = 0; h < NE; ++h)
        #pragma unroll
        for (int t = 0; t < 2; ++t)
            tokk[h][t] = idx_s[h * NK + 16 * (2 * nth + t) + lr];

    #pragma unroll
    for (int p = 0; p < 4; ++p) {
        for (int f = tid; f < 256 * 49; f += 384) outf[f] = 0.f;
        __syncthreads();

        #pragma unroll
        for (int h = 0; h < NE; ++h) {
            bf16x8 Aw = ld8(Wcomb_t + ((long)h * 192 + p * 48 + 16 * wcol + lr) * 32 + 4 * lg);
            #pragma unroll
            for (int t = 0; t < 2; ++t) {
                f32x4 acc = __builtin_amdgcn_mfma_f32_16x16x32_bf16(
                    Aw, Bt[h][t], (f32x4){0.f, 0.f, 0.f, 0.f}, 0, 0, 0);
                float* dst = outf + tokk[h][t] * 49 + 16 * wcol + 4 * lg;
                dst[0] += acc[0];
                dst[1] += acc[1];
                dst[2] += acc[2];
                dst[3] += acc[3];
            }
            __syncthreads();   // separate head intervals (cross-head clashes)
        }

        const int nf4 = (p == 3) ? 9 : 12;   // float4 cols this pass (c<180)
        for (int f = tid; f < 256 * nf4; f += 384) {
            int t = f / nf4, j = f % nf4;
            int c = 48 * p + 4 * j;
            float4 o;
            o.x = outf[t * 49 + 4 * j]     + bp[c];
            o.y = outf[t * 49 + 4 * j + 1] + bp[c + 1];
            o.z = outf[t * 49 + 4 * j + 2] + bp[c + 2];
            o.w = outf[t * 49 + 4 * j + 3] + bp[c + 3];
            long obase = (((long)b * NH + hb * 16 + (t >> 4)) * NW + wb * 16 + (t & 15)) * NC + c;
            *(float4*)(out + obase) = o;
        }
        __syncthreads();   // out-reads of outf done before next pass zeroes
    }
}

// ---------------------------------------------------------------------------
extern "C" void kernel_launch(void* const* d_in, const int* in_sizes, int n_in,
                              void* d_out, int out_size, void* d_ws, size_t ws_size,
                              hipStream_t stream) {
    const float* x    = (const float*)d_in[0];
    const float* Wr   = (const float*)d_in[1];
    const float* Wqkv = (const float*)d_in[2];
    const float* Wo   = (const float*)d_in[3];
    const float* Wp   = (const float*)d_in[4];
    const float* bp   = (const float*)d_in[5];
    float* out = (float*)d_out;

    char* ws = (char*)d_ws;
    unsigned short* Wqkv_t  = (unsigned short*)ws;                  // 221184 B
    unsigned short* Wcomb_t = (unsigned short*)(ws + 221184);       // 73728 B
    int*   idx_g  = (int*)(ws + 294912);                            // 3 MB
    float* vals_g = (float*)(ws + 294912 + (size_t)NWIN * NE * NK * 4);
    unsigned short* at_g = (unsigned short*)(ws + 294912 + 2 * (size_t)NWIN * NE * NK * 4);  // 48 MB

    k_prep<<<432, 256, 0, stream>>>(Wqkv, Wo, Wp, Wqkv_t, Wcomb_t);
    k_router_topk<<<NWIN, 256, 0, stream>>>(x, Wr, idx_g, vals_g);
    k_attn<<<3072, 256, 0, stream>>>(x, Wqkv_t, idx_g, vals_g, at_g);
    k_scatter<<<NWIN, 384, 0, stream>>>(at_g, Wcomb_t, bp, idx_g, out);
}

// Round 18
// 569.409 us; speedup vs baseline: 1.3488x; 1.0512x over previous
//
#include <hip/hip_runtime.h>
#include <math.h>

#define NB 8
#define NH 256
#define NW 256
#define NC 180
#define NE 6
#define HD 30
#define NL 256
#define NK 64
#define NWIN 2048

typedef __attribute__((ext_vector_type(8))) short bf16x8;
typedef __attribute__((ext_vector_type(4))) float f32x4;

union FU { bf16x8 f; unsigned u[4]; unsigned short s[8]; };

static __device__ __forceinline__ unsigned short f2bf(float x) {
    unsigned u = __float_as_uint(x);
    unsigned r = (u + 0x7FFFu + ((u >> 16) & 1u)) >> 16;
    return (unsigned short)r;
}
static __device__ __forceinline__ unsigned pk2(float a, float b) {
    return (unsigned)f2bf(a) | ((unsigned)f2bf(b) << 16);
}
// fragment load: elements {p[0..3], p[16..19]} — 8B-aligned rows
static __device__ __forceinline__ bf16x8 ld8(const unsigned short* p) {
    FU t;
    *(uint2*)&t.u[0] = *(const uint2*)p;
    *(uint2*)&t.u[2] = *(const uint2*)(p + 16);
    return t.f;
}
// fragment-contiguous load: 8 u16 in one uint4 (16B-aligned)
static __device__ __forceinline__ bf16x8 ld16(const unsigned short* p) {
    FU t;
    *(uint4*)&t.u[0] = *(const uint4*)p;
    return t.f;
}
// same element order, 4B-aligned rows (stride-34 LDS)
static __device__ __forceinline__ bf16x8 ld8q(const unsigned short* p) {
    FU t;
    t.u[0] = *(const unsigned*)p;
    t.u[1] = *(const unsigned*)(p + 2);
    t.u[2] = *(const unsigned*)(p + 16);
    t.u[3] = *(const unsigned*)(p + 18);
    return t.f;
}
static __device__ __forceinline__ bf16x8 pack8(float4 a, float4 b) {
    FU t;
    t.u[0] = pk2(a.x, a.y); t.u[1] = pk2(a.z, a.w);
    t.u[2] = pk2(b.x, b.y); t.u[3] = pk2(b.z, b.w);
    return t.f;
}

// ---------------------------------------------------------------------------
// prep — FRAGMENT-CONTIGUOUS layouts (single uint4 per lane at consumers):
//  Wqkv_t2: idx = (h*96+n')*192 + kt*32 + lg*8 + e ; value = Wqkv[h][k][n]
//           k = 32kt + 4lg + (e<4 ? e : 12+e); n' = sec*32+r, n = sec*30+r
//  Wcomb_t2: idx = (h*192+o)*32 + lg*8 + e ; value = (Wo_h @ Wp^T)^T[o][d]
//           d = 4lg + (e<4 ? e : 12+e)   (pads d>=30, o>=180, r>=30, k>=180 = 0)
// ---------------------------------------------------------------------------
__global__ __launch_bounds__(256) void k_prep(
    const float* __restrict__ Wqkv, const float* __restrict__ Wo,
    const float* __restrict__ Wp,
    unsigned short* __restrict__ Wqkv_t, unsigned short* __restrict__ Wcomb_t)
{
    int i = blockIdx.x * 256 + threadIdx.x;
    if (i < NE * 96 * 192) {
        int q = i / 192, rem = i % 192;
        int h = q / 96, np = q % 96;
        int kt = rem / 32, lg = (rem % 32) / 8, e = rem % 8;
        int k = 32 * kt + 4 * lg + (e < 4 ? e : 12 + e);
        int sec = np >> 5, r = np & 31;
        float v = (r < 30 && k < NC) ? Wqkv[((long)h * NC + k) * 90 + sec * 30 + r] : 0.f;
        Wqkv_t[i] = f2bf(v);
    }
    if (i < NE * 192 * 32) {
        int q = i / 32, rem = i % 32;
        int h = q / 192, o = q % 192;
        int lg = rem / 8, e = rem % 8;
        int d = 4 * lg + (e < 4 ? e : 12 + e);
        float acc = 0.f;
        if (o < NC && d < HD) {
            const float* wo = Wo + ((long)h * HD + d) * NC;
            const float* wp = Wp + (long)o * NC;
            for (int c = 0; c < NC; ++c) acc += wo[c] * wp[c];
        }
        Wcomb_t[i] = f2bf(acc);
    }
}

// ---------------------------------------------------------------------------
// Router: staging + logit + sigmoid phases VERBATIM from round 1 (those
// compiled float bits match the np reference's selection exactly — do not
// touch). Selection: exact bitonic sort on sigmoid bits (round-13-proven).
// ---------------------------------------------------------------------------
__global__ __launch_bounds__(256) void k_router_topk(
    const float* __restrict__ x, const float* __restrict__ Wr,
    int* __restrict__ idx_g, float* __restrict__ vals_g)
{
    __shared__ float wr_s[NE * NC];
    __shared__ __align__(16) float xs[32 * 181];   // overlaid by keys after logits
    __shared__ float lg[NE * NL];

    const int w   = blockIdx.x;
    const int tid = threadIdx.x;
    const int b = w >> 8, hb = (w >> 4) & 15, wb = w & 15;
    const long win_base = (((long)b * NH + hb * 16) * NW + wb * 16) * NC;

    for (int f = tid; f < NE * NC; f += 256) wr_s[f] = Wr[f];
    __syncthreads();

    for (int tile = 0; tile < 8; ++tile) {
        for (int f = tid; f < 32 * NC; f += 256) {
            int tl = f / NC, ch = f % NC;
            int tok = tile * 32 + tl;
            int r = tok >> 4, cl = tok & 15;
            xs[tl * 181 + ch] = x[win_base + ((long)r * NW + cl) * NC + ch];
        }
        __syncthreads();
        if (tid < 192) {
            int tl = tid & 31, e = tid >> 5;
            float acc = 0.f;
            for (int c = 0; c < NC; ++c) acc += xs[tl * 181 + c] * wr_s[e * NC + c];
            lg[e * NL + tile * 32 + tl] = 1.0f / (1.0f + expf(-acc));
        }
        __syncthreads();
    }

    // ---- exact top-63 via bitonic sort of composite keys (bits identical) --
    unsigned long long* keys = (unsigned long long*)xs;  // xs dead; barriers pin
    #pragma unroll
    for (int e = 0; e < NE; ++e) {
        unsigned kb = __float_as_uint(lg[e * NL + tid]);
        unsigned long long comp =
            ((unsigned long long)kb << 32) | (unsigned)(0xFFFFFFFFu - tid);
        if (tid == 0) comp = 0ull;   // token 0 excluded from ranked list
        keys[e * NL + tid] = comp;
    }
    __syncthreads();

    for (int k = 2; k <= 256; k <<= 1) {
        for (int j = k >> 1; j > 0; j >>= 1) {
            const int i = tid, ixj = i ^ j;
            if (ixj > i) {
                const bool up = ((i & k) == 0);
                #pragma unroll
                for (int e = 0; e < NE; ++e) {
                    unsigned long long a  = keys[e * NL + i];
                    unsigned long long bv = keys[e * NL + ixj];
                    bool sw = up ? (a < bv) : (a > bv);   // descending sort
                    if (sw) { keys[e * NL + i] = bv; keys[e * NL + ixj] = a; }
                }
            }
            __syncthreads();
        }
    }

    if (tid < NK - 1) {   // sorted position == rank; slots 1..63
        #pragma unroll
        for (int e = 0; e < NE; ++e) {
            unsigned long long kk = keys[e * NL + tid];
            int t = (int)(0xFFFFFFFFu - (unsigned)kk);
            idx_g[(w * NE + e) * NK + 1 + tid]  = t;
            vals_g[(w * NE + e) * NK + 1 + tid] = __uint_as_float((unsigned)(kk >> 32));
        }
    }
    if (tid == 0) {
        #pragma unroll
        for (int e = 0; e < NE; ++e) {
            idx_g[(w * NE + e) * NK]  = 0;
            vals_g[(w * NE + e) * NK] = lg[e * NL];
        }
    }
}

// ---------------------------------------------------------------------------
// k_attn: one WAVE per (window, head), w-major + XCD swizzle (consecutive
// w-major blocks share a window's token rows -> colocate on one XCD's L2).
// at_g FRAGMENT-CONTIGUOUS: row*32 + 8lg holds the lane's uint4 -> a wave's
// store is 16 rows x 64 B = 1024 B contiguous (round-17: 2x write amp from
// stride-64 8B stores).
// ---------------------------------------------------------------------------
__global__ __launch_bounds__(256, 3) void k_attn(
    const float* __restrict__ x,
    const unsigned short* __restrict__ Wqkv_t,
    const int* __restrict__ idx_g, const float* __restrict__ vals_g,
    unsigned short* __restrict__ at_g)
{
    __shared__ char sm[34816];
    const int tid = threadIdx.x;
    const int wv = tid >> 6;
    const int ln = tid & 63;
    const int lr = ln & 15;
    const int lg = ln >> 4;

    // XCD swizzle: dispatch d -> block (d%8)*384 + d/8 (bijective, 3072=8*384)
    const int bid = (blockIdx.x & 7) * 384 + (blockIdx.x >> 3);
    const int id = bid * 4 + wv;             // w-major: id = w*6 + h
    const int w = id / 6;
    const int h = id % 6;
    const int b = w >> 8, hb = (w >> 4) & 15, wb = w & 15;
    const long win_base = (((long)b * NH + hb * 16) * NW + wb * 16) * NC;

    unsigned short* q_s = (unsigned short*)(sm + wv * 8704);
    unsigned short* k_s = q_s + 2176;

    int tokr[4];
    #pragma unroll
    for (int t = 0; t < 4; ++t)
        tokr[t] = idx_g[((long)w * NE + h) * NK + 16 * t + lr];

    // --- QKV = gather(x) @ Wqkv_t : M=64, N=96, K=192 ---
    f32x4 acc[6][4];
    #pragma unroll
    for (int nt = 0; nt < 6; ++nt)
        #pragma unroll
        for (int mt = 0; mt < 4; ++mt) acc[nt][mt] = (f32x4){0.f, 0.f, 0.f, 0.f};

    const unsigned short* bb = Wqkv_t + ((long)h * 96 + lr) * 192 + 8 * lg;
    #pragma unroll
    for (int kt = 0; kt < 6; ++kt) {
        bf16x8 Amt[4];
        #pragma unroll
        for (int mt = 0; mt < 4; ++mt) {
            const float* xr = x + win_base +
                ((long)(tokr[mt] >> 4) * NW + (tokr[mt] & 15)) * NC;
            if (kt < 5) {
                float4 a  = *(const float4*)(xr + 4 * lg + 32 * kt);
                float4 b2 = *(const float4*)(xr + 4 * lg + 32 * kt + 16);
                Amt[mt] = pack8(a, b2);
            } else {
                float4 a  = *(const float4*)(xr + 4 * lg + 160);
                float4 b2 = make_float4(0.f, 0.f, 0.f, 0.f);
                if (lg == 0) b2 = *(const float4*)(xr + 176);
                Amt[mt] = pack8(a, b2);
            }
        }
        #pragma unroll
        for (int nt = 0; nt < 6; ++nt) {
            bf16x8 B = ld16(bb + nt * (16 * 192) + kt * 32);
            #pragma unroll
            for (int mt = 0; mt < 4; ++mt)
                acc[nt][mt] = __builtin_amdgcn_mfma_f32_16x16x32_bf16(Amt[mt], B, acc[nt][mt], 0, 0, 0);
        }
    }

    // --- write Q/K (nt 0..3) to LDS transpose buffers; V (nt 4,5) in regs ---
    #pragma unroll
    for (int nt = 0; nt < 4; ++nt) {
        unsigned short* dst = (nt < 2 ? q_s : k_s) + 16 * (nt & 1) + lr;
        #pragma unroll
        for (int mt = 0; mt < 4; ++mt) {
            int row = 16 * mt + 4 * lg;
            dst[(row + 0) * 34] = f2bf(acc[nt][mt][0]);
            dst[(row + 1) * 34] = f2bf(acc[nt][mt][1]);
            dst[(row + 2) * 34] = f2bf(acc[nt][mt][2]);
            dst[(row + 3) * 34] = f2bf(acc[nt][mt][3]);
        }
    }
    unsigned V32[4][2][2];
    #pragma unroll
    for (int j = 0; j < 2; ++j)
        #pragma unroll
        for (int mt = 0; mt < 4; ++mt) {
            V32[mt][j][0] = pk2(acc[4 + j][mt][0], acc[4 + j][mt][1]);
            V32[mt][j][1] = pk2(acc[4 + j][mt][2], acc[4 + j][mt][3]);
        }

    // TBAA pin: u16 ds_writes above vs u32 ds_reads below (round-7 lesson)
    __syncthreads();

    // --- scores^T = mfma(K, Q) ---
    f32x4 s[4][4];
    {
        bf16x8 Bq[4];
        #pragma unroll
        for (int nt = 0; nt < 4; ++nt)
            Bq[nt] = ld8q(q_s + (16 * nt + lr) * 34 + 4 * lg);
        #pragma unroll
        for (int amt = 0; amt < 4; ++amt) {
            bf16x8 Ak = ld8q(k_s + (16 * amt + lr) * 34 + 4 * lg);
            #pragma unroll
            for (int nt = 0; nt < 4; ++nt)
                s[amt][nt] = __builtin_amdgcn_mfma_f32_16x16x32_bf16(
                    Ak, Bq[nt], (f32x4){0.f, 0.f, 0.f, 0.f}, 0, 0, 0);
        }
    }

    // --- in-register softmax + gate ---
    float gsc[4];
    #pragma unroll
    for (int nt = 0; nt < 4; ++nt) {
        float mx = -1e30f;
        #pragma unroll
        for (int amt = 0; amt < 4; ++amt)
            #pragma unroll
            for (int r = 0; r < 4; ++r) mx = fmaxf(mx, s[amt][nt][r]);
        mx = fmaxf(mx, __shfl_xor(mx, 16));
        mx = fmaxf(mx, __shfl_xor(mx, 32));
        float sum = 0.f;
        #pragma unroll
        for (int amt = 0; amt < 4; ++amt)
            #pragma unroll
            for (int r = 0; r < 4; ++r) {
                float p = __expf((s[amt][nt][r] - mx) * 0.18257418583505536f);
                s[amt][nt][r] = p;
                sum += p;
            }
        sum += __shfl_xor(sum, 16);
        sum += __shfl_xor(sum, 32);
        gsc[nt] = vals_g[((long)w * NE + h) * NK + 16 * nt + lr] / sum;
    }

    // --- attn^T = mfma(V^T, P^T); pack as B-fragments ---
    bf16x8 Av[2][2];
    #pragma unroll
    for (int amt = 0; amt < 2; ++amt)
        #pragma unroll
        for (int kt = 0; kt < 2; ++kt) {
            FU t;
            t.u[0] = V32[2 * kt][amt][0];
            t.u[1] = V32[2 * kt][amt][1];
            t.u[2] = V32[2 * kt + 1][amt][0];
            t.u[3] = V32[2 * kt + 1][amt][1];
            Av[amt][kt] = t.f;
        }
    #pragma unroll
    for (int nt = 0; nt < 4; ++nt) {
        bf16x8 Pb[2];
        float g = gsc[nt];
        #pragma unroll
        for (int kt = 0; kt < 2; ++kt) {
            FU t;
            t.u[0] = pk2(s[2 * kt][nt][0] * g, s[2 * kt][nt][1] * g);
            t.u[1] = pk2(s[2 * kt][nt][2] * g, s[2 * kt][nt][3] * g);
            t.u[2] = pk2(s[2 * kt + 1][nt][0] * g, s[2 * kt + 1][nt][1] * g);
            t.u[3] = pk2(s[2 * kt + 1][nt][2] * g, s[2 * kt + 1][nt][3] * g);
            Pb[kt] = t.f;
        }
        f32x4 a0 = (f32x4){0.f, 0.f, 0.f, 0.f};
        a0 = __builtin_amdgcn_mfma_f32_16x16x32_bf16(Av[0][0], Pb[0], a0, 0, 0, 0);
        a0 = __builtin_amdgcn_mfma_f32_16x16x32_bf16(Av[0][1], Pb[1], a0, 0, 0, 0);
        f32x4 a1 = (f32x4){0.f, 0.f, 0.f, 0.f};
        a1 = __builtin_amdgcn_mfma_f32_16x16x32_bf16(Av[1][0], Pb[0], a1, 0, 0, 0);
        a1 = __builtin_amdgcn_mfma_f32_16x16x32_bf16(Av[1][1], Pb[1], a1, 0, 0, 0);
        // fragment-contiguous store: wave covers 16 rows x 64 B contiguous
        unsigned short* row = at_g + (((long)h * NWIN + w) * 64 + 16 * nt + lr) * 32 + 8 * lg;
        *(uint4*)row = make_uint4(pk2(a0[0], a0[1]), pk2(a0[2], a0[3]),
                                  pk2(a1[0], a1[1]), pk2(a1[2], a1[3]));
    }
}

// ---------------------------------------------------------------------------
// k_scatter: ONE block per window, 4 channel-passes inside, fully unrolled
// (rule #20: runtime-indexed register arrays spill regardless of budget).
// Race-free partition per pass (round-14-proven): wave = (nt-half, wcol);
// within one head nt-blocks are row-disjoint, wcol slices col-disjoint;
// per-head __syncthreads() separates cross-head (tok,col) collisions.
// Fragment-contiguous uint4 loads for Bt and Aw; float4 out-writes.
// ---------------------------------------------------------------------------
__global__ __launch_bounds__(384, 2) void k_scatter(
    const unsigned short* __restrict__ at_g,
    const unsigned short* __restrict__ Wcomb_t,
    const float* __restrict__ bp,
    const int* __restrict__ idx_g,
    float* __restrict__ out)
{
    __shared__ float outf[256 * 49];
    __shared__ unsigned char idx_s[NE * NK];

    const int w = blockIdx.x;
    const int tid = threadIdx.x;
    const int b = w >> 8, hb = (w >> 4) & 15, wb = w & 15;

    const int wv = tid >> 6;
    const int ln = tid & 63;
    const int lr = ln & 15;
    const int lg = ln >> 4;

    idx_s[tid] = (unsigned char)idx_g[(long)w * NE * NK + tid];  // 384 == NE*NK

    const int wcol = wv % 3;
    const int nth  = wv / 3;            // 0 or 1: nt-blocks {0,1} or {2,3}

    // --- load all B-fragments for this wave's nt-half once (48 VGPR) ---
    bf16x8 Bt[NE][2];
    #pragma unroll
    for (int h = 0; h < NE; ++h)
        #pragma unroll
        for (int t = 0; t < 2; ++t) {
            const int nt = 2 * nth + t;
            Bt[h][t] = ld16(at_g + (((long)h * NWIN + w) * 64 + 16 * nt + lr) * 32 + 8 * lg);
        }
    __syncthreads();   // idx_s visible

    int tokk[NE][2];
    #pragma unroll
    for (int h = 0; h < NE; ++h)
        #pragma unroll
        for (int t = 0; t < 2; ++t)
            tokk[h][t] = idx_s[h * NK + 16 * (2 * nth + t) + lr];

    #pragma unroll
    for (int p = 0; p < 4; ++p) {
        for (int f = tid; f < 256 * 49; f += 384) outf[f] = 0.f;
        __syncthreads();

        #pragma unroll
        for (int h = 0; h < NE; ++h) {
            bf16x8 Aw = ld16(Wcomb_t + ((long)h * 192 + p * 48 + 16 * wcol + lr) * 32 + 8 * lg);
            #pragma unroll
            for (int t = 0; t < 2; ++t) {
                f32x4 acc = __builtin_amdgcn_mfma_f32_16x16x32_bf16(
                    Aw, Bt[h][t], (f32x4){0.f, 0.f, 0.f, 0.f}, 0, 0, 0);
                float* dst = outf + tokk[h][t] * 49 + 16 * wcol + 4 * lg;
                dst[0] += acc[0];
                dst[1] += acc[1];
                dst[2] += acc[2];
                dst[3] += acc[3];
            }
            __syncthreads();   // separate head intervals (cross-head clashes)
        }

        const int nf4 = (p == 3) ? 9 : 12;   // float4 cols this pass (c<180)
        for (int f = tid; f < 256 * nf4; f += 384) {
            int t = f / nf4, j = f % nf4;
            int c = 48 * p + 4 * j;
            float4 o;
            o.x = outf[t * 49 + 4 * j]     + bp[c];
            o.y = outf[t * 49 + 4 * j + 1] + bp[c + 1];
            o.z = outf[t * 49 + 4 * j + 2] + bp[c + 2];
            o.w = outf[t * 49 + 4 * j + 3] + bp[c + 3];
            long obase = (((long)b * NH + hb * 16 + (t >> 4)) * NW + wb * 16 + (t & 15)) * NC + c;
            *(float4*)(out + obase) = o;
        }
        __syncthreads();   // out-reads of outf done before next pass zeroes
    }
}

// ---------------------------------------------------------------------------
extern "C" void kernel_launch(void* const* d_in, const int* in_sizes, int n_in,
                              void* d_out, int out_size, void* d_ws, size_t ws_size,
                              hipStream_t stream) {
    const float* x    = (const float*)d_in[0];
    const float* Wr   = (const float*)d_in[1];
    const float* Wqkv = (const float*)d_in[2];
    const float* Wo   = (const float*)d_in[3];
    const float* Wp   = (const float*)d_in[4];
    const float* bp   = (const float*)d_in[5];
    float* out = (float*)d_out;

    char* ws = (char*)d_ws;
    unsigned short* Wqkv_t  = (unsigned short*)ws;                  // 221184 B
    unsigned short* Wcomb_t = (unsigned short*)(ws + 221184);       // 73728 B
    int*   idx_g  = (int*)(ws + 294912);                            // 3 MB
    float* vals_g = (float*)(ws + 294912 + (size_t)NWIN * NE * NK * 4);
    unsigned short* at_g = (unsigned short*)(ws + 294912 + 2 * (size_t)NWIN * NE * NK * 4);  // 48 MB

    k_prep<<<432, 256, 0, stream>>>(Wqkv, Wo, Wp, Wqkv_t, Wcomb_t);
    k_router_topk<<<NWIN, 256, 0, stream>>>(x, Wr, idx_g, vals_g);
    k_attn<<<3072, 256, 0, stream>>>(x, Wqkv_t, idx_g, vals_g, at_g);
    k_scatter<<<NWIN, 384, 0, stream>>>(at_g, Wcomb_t, bp, idx_g, out);
}